// Round 2
// baseline (347.926 us; speedup 1.0000x reference)
//
#include <hip/hip_runtime.h>

#define N_NODES 50000
#define N_EDGES 800000
#define D 128

// ---------------------------------------------------------------------------
// K1: count in-degree per dst node (800K int atomics; HW coalesces per-wave)
// ---------------------------------------------------------------------------
__global__ void deg_kernel(const int* __restrict__ dst, int* __restrict__ deg) {
  int e = blockIdx.x * blockDim.x + threadIdx.x;
  if (e < N_EDGES) atomicAdd(&deg[dst[e]], 1);
}

// ---------------------------------------------------------------------------
// K2: single-block exclusive scan of deg -> offs[0..N_NODES]
// shuffle-based wave scan, 2 barriers per 1024-chunk (49 chunks)
// ---------------------------------------------------------------------------
__global__ void scan_kernel(const int* __restrict__ deg, int* __restrict__ offs) {
  __shared__ int wsum[16];
  __shared__ int woff[16];
  __shared__ int tot_s;
  const int tid = threadIdx.x;
  const int lane = tid & 63;
  const int wid = tid >> 6;
  int carry = 0;
  const int nchunks = (N_NODES + 1023) / 1024;
  for (int ch = 0; ch < nchunks; ++ch) {
    int i = ch * 1024 + tid;
    int v = (i < N_NODES) ? deg[i] : 0;
    int val = v;
#pragma unroll
    for (int off = 1; off < 64; off <<= 1) {
      int t = __shfl_up(val, off, 64);
      if (lane >= off) val += t;
    }
    if (lane == 63) wsum[wid] = val;
    __syncthreads();
    if (tid < 16) {
      int s = wsum[tid];
      int sc = s;
#pragma unroll
      for (int off = 1; off < 16; off <<= 1) {
        int t = __shfl_up(sc, off, 64);
        if (tid >= off) sc += t;
      }
      woff[tid] = sc - s;           // exclusive offset of wave wid
      if (tid == 15) tot_s = sc;    // chunk total
    }
    __syncthreads();
    int excl = (val - v) + woff[wid];
    if (i < N_NODES) offs[i] = carry + excl;
    carry += tot_s;  // stable until next chunk's first barrier
  }
  if (tid == 0) offs[N_NODES] = carry;
}

// ---------------------------------------------------------------------------
// K3: fill CSR edge array: eidx[offs[dst] + slot] = src
// ---------------------------------------------------------------------------
__global__ void fill_kernel(const int* __restrict__ src, const int* __restrict__ dst,
                            const int* __restrict__ offs, int* __restrict__ cursor,
                            int* __restrict__ eidx) {
  int e = blockIdx.x * blockDim.x + threadIdx.x;
  if (e < N_EDGES) {
    int d = dst[e];
    int p = atomicAdd(&cursor[d], 1);
    eidx[offs[d] + p] = src[e];
  }
}

// ---------------------------------------------------------------------------
// K4: per-node gather + mean, written into OUT (used as h staging; the GEMM
// consumes it in-place). 32 lanes per node, float4 per lane. No atomics.
// ---------------------------------------------------------------------------
__global__ __launch_bounds__(256) void aggregate_kernel(
    const float* __restrict__ feat, const int* __restrict__ offs,
    const int* __restrict__ eidx, float* __restrict__ h) {
  int g = (blockIdx.x * blockDim.x + threadIdx.x) >> 5;  // node id
  int lane = threadIdx.x & 31;
  if (g >= N_NODES) return;
  int beg = offs[g], end = offs[g + 1];
  float4 acc = {0.f, 0.f, 0.f, 0.f};
  for (int j = beg; j < end; ++j) {
    int s = eidx[j];
    float4 f = *reinterpret_cast<const float4*>(feat + (size_t)s * D + lane * 4);
    acc.x += f.x; acc.y += f.y; acc.z += f.z; acc.w += f.w;
  }
  float scale = 1.0f / fmaxf((float)(end - beg), 1.0f);
  float4 o = {acc.x * scale, acc.y * scale, acc.z * scale, acc.w * scale};
  *reinterpret_cast<float4*>(h + (size_t)g * D + lane * 4) = o;
}

// ---------------------------------------------------------------------------
// K5: in-place fused GEMM: out = feat@Ws + h@Wn + b, where h lives in `out`.
// Block = 256 threads, 64 rows. Stage 64 feat-rows + 64 h-rows into LDS
// (stride 132: 2-way bank conflict only = free), barrier, then each thread
// computes 4 rows x 8 cols. out-row r depends only on h-row r, and each row
// is staged+written by exactly one block -> in-place safe.
// ---------------------------------------------------------------------------
__global__ __launch_bounds__(256) void gemm_kernel(
    const float* __restrict__ feat, const float* __restrict__ Ws,
    const float* __restrict__ Wn, const float* __restrict__ bias,
    float* __restrict__ out) {
  __shared__ float f_lds[64][132];
  __shared__ float h_lds[64][132];
  const int tid = threadIdx.x;
  const int r0 = blockIdx.x * 64;

  // stage: thread t -> row t>>2, 32-col span (t&3)*32, both arrays
  {
    int row = tid >> 2;
    int c0 = (tid & 3) * 32;
    int r = r0 + row;
    if (r < N_NODES) {
      const float* fs = feat + (size_t)r * D + c0;
      const float* hs = out + (size_t)r * D + c0;
#pragma unroll
      for (int j = 0; j < 8; ++j) {
        float4 a = *reinterpret_cast<const float4*>(fs + j * 4);
        float4 b = *reinterpret_cast<const float4*>(hs + j * 4);
        *reinterpret_cast<float4*>(&f_lds[row][c0 + j * 4]) = a;
        *reinterpret_cast<float4*>(&h_lds[row][c0 + j * 4]) = b;
      }
    } else {
      float4 z = {0.f, 0.f, 0.f, 0.f};
#pragma unroll
      for (int j = 0; j < 8; ++j) {
        *reinterpret_cast<float4*>(&f_lds[row][c0 + j * 4]) = z;
        *reinterpret_cast<float4*>(&h_lds[row][c0 + j * 4]) = z;
      }
    }
  }
  __syncthreads();

  const int rs = tid & 15;        // row slot: rows rs, rs+16, rs+32, rs+48
  const int n = (tid >> 4) * 8;   // col start
  float acc[4][8];
#pragma unroll
  for (int m = 0; m < 4; ++m)
#pragma unroll
    for (int j = 0; j < 8; ++j) acc[m][j] = 0.f;

#pragma unroll 4
  for (int k = 0; k < D; ++k) {
    float4 w0 = *reinterpret_cast<const float4*>(Ws + k * D + n);
    float4 w1 = *reinterpret_cast<const float4*>(Ws + k * D + n + 4);
    float4 v0 = *reinterpret_cast<const float4*>(Wn + k * D + n);
    float4 v1 = *reinterpret_cast<const float4*>(Wn + k * D + n + 4);
#pragma unroll
    for (int m = 0; m < 4; ++m) {
      float xf = f_lds[rs + m * 16][k];
      float xh = h_lds[rs + m * 16][k];
      acc[m][0] = fmaf(xf, w0.x, fmaf(xh, v0.x, acc[m][0]));
      acc[m][1] = fmaf(xf, w0.y, fmaf(xh, v0.y, acc[m][1]));
      acc[m][2] = fmaf(xf, w0.z, fmaf(xh, v0.z, acc[m][2]));
      acc[m][3] = fmaf(xf, w0.w, fmaf(xh, v0.w, acc[m][3]));
      acc[m][4] = fmaf(xf, w1.x, fmaf(xh, v1.x, acc[m][4]));
      acc[m][5] = fmaf(xf, w1.y, fmaf(xh, v1.y, acc[m][5]));
      acc[m][6] = fmaf(xf, w1.z, fmaf(xh, v1.z, acc[m][6]));
      acc[m][7] = fmaf(xf, w1.w, fmaf(xh, v1.w, acc[m][7]));
    }
  }

  float4 b0 = *reinterpret_cast<const float4*>(bias + n);
  float4 b1 = *reinterpret_cast<const float4*>(bias + n + 4);
#pragma unroll
  for (int m = 0; m < 4; ++m) {
    int r = r0 + rs + m * 16;
    if (r < N_NODES) {
      float4 o0 = {acc[m][0] + b0.x, acc[m][1] + b0.y,
                   acc[m][2] + b0.z, acc[m][3] + b0.w};
      float4 o1 = {acc[m][4] + b1.x, acc[m][5] + b1.y,
                   acc[m][6] + b1.z, acc[m][7] + b1.w};
      *reinterpret_cast<float4*>(out + (size_t)r * D + n) = o0;
      *reinterpret_cast<float4*>(out + (size_t)r * D + n + 4) = o1;
    }
  }
}

// ---------------------------------------------------------------------------
extern "C" void kernel_launch(void* const* d_in, const int* in_sizes, int n_in,
                              void* d_out, int out_size, void* d_ws, size_t ws_size,
                              hipStream_t stream) {
  const float* feat = (const float*)d_in[0];
  const int* src    = (const int*)d_in[1];
  const int* dst    = (const int*)d_in[2];
  const float* Ws   = (const float*)d_in[3];
  const float* Wn   = (const float*)d_in[4];
  const float* bias = (const float*)d_in[5];
  float* out = (float*)d_out;

  // workspace layout: ints only, ~3.8 MB total
  int* offs   = (int*)d_ws;              // N_NODES+1 (padded to 50004)
  int* deg    = offs + 50004;            // N_NODES
  int* cursor = deg + 50000;             // N_NODES
  int* eidx   = cursor + 50000;          // N_EDGES

  hipMemsetAsync(deg, 0, N_NODES * sizeof(int), stream);
  hipMemsetAsync(cursor, 0, N_NODES * sizeof(int), stream);

  deg_kernel<<<(N_EDGES + 255) / 256, 256, 0, stream>>>(dst, deg);
  scan_kernel<<<1, 1024, 0, stream>>>(deg, offs);
  fill_kernel<<<(N_EDGES + 255) / 256, 256, 0, stream>>>(src, dst, offs, cursor, eidx);
  aggregate_kernel<<<(N_NODES * 32 + 255) / 256, 256, 0, stream>>>(feat, offs, eidx, out);
  gemm_kernel<<<(N_NODES + 63) / 64, 256, 0, stream>>>(feat, Ws, Wn, bias, out);
}

// Round 4
// 228.906 us; speedup vs baseline: 1.5200x; 1.5200x over previous
//
#include <hip/hip_runtime.h>

#define N_NODES 50000
#define N_EDGES 800000
#define D 128

typedef __attribute__((ext_vector_type(8))) short bf16x8;
typedef __attribute__((ext_vector_type(4))) float f32x4;

__device__ __forceinline__ unsigned short f2bf(float f) {
  unsigned u = __float_as_uint(f);
  u = (u + 0x7FFFu + ((u >> 16) & 1u)) >> 16;  // RNE
  return (unsigned short)u;
}

// ---------------------------------------------------------------------------
// feat fp32 -> bf16 (6.4M elems, 8 per thread)
// ---------------------------------------------------------------------------
__global__ void cvt_feat_kernel(const float* __restrict__ feat,
                                unsigned short* __restrict__ fb) {
  int i = blockIdx.x * blockDim.x + threadIdx.x;  // 800000 threads exactly
  float4 a = ((const float4*)feat)[2 * i];
  float4 b = ((const float4*)feat)[2 * i + 1];
  union { unsigned short s[8]; uint4 u; } p;
  p.s[0] = f2bf(a.x); p.s[1] = f2bf(a.y); p.s[2] = f2bf(a.z); p.s[3] = f2bf(a.w);
  p.s[4] = f2bf(b.x); p.s[5] = f2bf(b.y); p.s[6] = f2bf(b.z); p.s[7] = f2bf(b.w);
  ((uint4*)fb)[i] = p.u;
}

// ---------------------------------------------------------------------------
// W prepack: wt[n*256 + k] = bf16(Wcat[k][n]), Wcat = [Ws; Wn] (256 x 128)
// ---------------------------------------------------------------------------
__global__ void prepack_w_kernel(const float* __restrict__ Ws,
                                 const float* __restrict__ Wn,
                                 unsigned short* __restrict__ wt) {
  int t = blockIdx.x * blockDim.x + threadIdx.x;  // 32768
  int n = t >> 8, k = t & 255;
  float v = (k < 128) ? Ws[k * 128 + n] : Wn[(k - 128) * 128 + n];
  wt[t] = f2bf(v);
}

// ---------------------------------------------------------------------------
// K1: in-degree count
// ---------------------------------------------------------------------------
__global__ void deg_kernel(const int* __restrict__ dst, int* __restrict__ deg) {
  int e = blockIdx.x * blockDim.x + threadIdx.x;
  if (e < N_EDGES) atomicAdd(&deg[dst[e]], 1);
}

// ---------------------------------------------------------------------------
// K2a/b/c: 3-phase exclusive scan of deg -> offs[0..N]
// ---------------------------------------------------------------------------
__global__ void scan_local_kernel(const int* __restrict__ deg, int* __restrict__ offs,
                                  int* __restrict__ bsum) {
  __shared__ int wsum[16];
  __shared__ int woff[16];
  __shared__ int tot_s;
  const int tid = threadIdx.x;
  const int lane = tid & 63;
  const int wid = tid >> 6;
  int i = blockIdx.x * 1024 + tid;
  int v = (i < N_NODES) ? deg[i] : 0;
  int val = v;
#pragma unroll
  for (int off = 1; off < 64; off <<= 1) {
    int t = __shfl_up(val, off, 64);
    if (lane >= off) val += t;
  }
  if (lane == 63) wsum[wid] = val;
  __syncthreads();
  if (tid < 16) {
    int s = wsum[tid];
    int sc = s;
#pragma unroll
    for (int off = 1; off < 16; off <<= 1) {
      int t = __shfl_up(sc, off, 64);
      if (tid >= off) sc += t;
    }
    woff[tid] = sc - s;
    if (tid == 15) tot_s = sc;
  }
  __syncthreads();
  if (i < N_NODES) offs[i] = (val - v) + woff[wid];
  if (tid == 0) bsum[blockIdx.x] = tot_s;
}

__global__ void scan_bsum_kernel(int* __restrict__ bsum, int* __restrict__ offs) {
  int t = threadIdx.x;  // 64 threads, 1 wave; 49 valid
  int v = (t < 49) ? bsum[t] : 0;
  int val = v;
#pragma unroll
  for (int off = 1; off < 64; off <<= 1) {
    int x = __shfl_up(val, off, 64);
    if (t >= off) val += x;
  }
  if (t < 49) bsum[t] = val - v;        // exclusive carry per block
  if (t == 48) offs[N_NODES] = val;     // grand total
}

__global__ void add_carry_kernel(int* __restrict__ offs, const int* __restrict__ bsum) {
  int i = blockIdx.x * blockDim.x + threadIdx.x;
  if (i < N_NODES) offs[i] += bsum[i >> 10];
}

// ---------------------------------------------------------------------------
// K3: CSR fill
// ---------------------------------------------------------------------------
__global__ void fill_kernel(const int* __restrict__ src, const int* __restrict__ dst,
                            const int* __restrict__ offs, int* __restrict__ cursor,
                            int* __restrict__ eidx) {
  int e = blockIdx.x * blockDim.x + threadIdx.x;
  if (e < N_EDGES) {
    int d = dst[e];
    int p = atomicAdd(&cursor[d], 1);
    eidx[offs[d] + p] = src[e];
  }
}

// ---------------------------------------------------------------------------
// K4: gather-mean over bf16 feat; 16 lanes/node, ushort8 (16B) per lane,
// 4-edge unrolled for MLP. Writes h (fp32) into d_out.
// ---------------------------------------------------------------------------
__global__ __launch_bounds__(256) void aggregate_bf_kernel(
    const unsigned short* __restrict__ fb, const int* __restrict__ offs,
    const int* __restrict__ eidx, float* __restrict__ h) {
  int g = (blockIdx.x * blockDim.x + threadIdx.x) >> 4;
  int lane = threadIdx.x & 15;
  if (g >= N_NODES) return;
  int beg = offs[g], end = offs[g + 1];
  float acc[8] = {0.f, 0.f, 0.f, 0.f, 0.f, 0.f, 0.f, 0.f};
  const unsigned short* fl = fb + lane * 8;
#define ACC8(v)                                                            \
  {                                                                        \
    acc[0] += __uint_as_float((v).x << 16);                                \
    acc[1] += __uint_as_float((v).x & 0xFFFF0000u);                        \
    acc[2] += __uint_as_float((v).y << 16);                                \
    acc[3] += __uint_as_float((v).y & 0xFFFF0000u);                        \
    acc[4] += __uint_as_float((v).z << 16);                                \
    acc[5] += __uint_as_float((v).z & 0xFFFF0000u);                        \
    acc[6] += __uint_as_float((v).w << 16);                                \
    acc[7] += __uint_as_float((v).w & 0xFFFF0000u);                        \
  }
  int j = beg;
  for (; j + 3 < end; j += 4) {
    int s0 = eidx[j], s1 = eidx[j + 1], s2 = eidx[j + 2], s3 = eidx[j + 3];
    uint4 v0 = *(const uint4*)(fl + (size_t)s0 * D);
    uint4 v1 = *(const uint4*)(fl + (size_t)s1 * D);
    uint4 v2 = *(const uint4*)(fl + (size_t)s2 * D);
    uint4 v3 = *(const uint4*)(fl + (size_t)s3 * D);
    ACC8(v0); ACC8(v1); ACC8(v2); ACC8(v3);
  }
  for (; j < end; ++j) {
    uint4 v = *(const uint4*)(fl + (size_t)eidx[j] * D);
    ACC8(v);
  }
#undef ACC8
  float scale = 1.0f / fmaxf((float)(end - beg), 1.0f);
  float* op = h + (size_t)g * D + lane * 8;
  float4 o0 = {acc[0] * scale, acc[1] * scale, acc[2] * scale, acc[3] * scale};
  float4 o1 = {acc[4] * scale, acc[5] * scale, acc[6] * scale, acc[7] * scale};
  *(float4*)op = o0;
  *(float4*)(op + 4) = o1;
}

// ---------------------------------------------------------------------------
// K5: MFMA GEMM: out = [fb | bf16(h)] @ Wcat + bias, h read in-place from out.
// 512 thr = 8 waves x 16 rows = 128 rows/block. Wt (n-major, pad 264) in LDS.
// Per wave: prefetch all 8 A-frags (1 global latency exposure), then
// 64 x ds_read_b128 + mfma_f32_16x16x32_bf16. In-place safe: all h reads
// happen before the single barrier; all out writes after the MFMA loop.
// ---------------------------------------------------------------------------
__global__ __launch_bounds__(512) void gemm_mfma_kernel(
    const unsigned short* __restrict__ fb, const unsigned short* __restrict__ wt,
    const float* __restrict__ bias, float* out) {
  __shared__ unsigned short wt_lds[128 * 264];  // 67584 B
  const int tid = threadIdx.x;
  const int w = tid >> 6;
  const int l = tid & 63;
  const int li = l & 15;
  const int lg = l >> 4;
  const int koff = lg * 8;
  const int r0 = blockIdx.x * 128 + w * 16;
  int arow = r0 + li;
  if (arow > N_NODES - 1) arow = N_NODES - 1;  // clamp; results discarded

  // A prefetch: feat half (bf16 direct)
  bf16x8 afrag[8];
  const unsigned short* fbp = fb + (size_t)arow * D + koff;
#pragma unroll
  for (int ks = 0; ks < 4; ++ks)
    afrag[ks] = *(const bf16x8*)(fbp + ks * 32);
  // A prefetch: h half (fp32 from out, convert below)
  const float* hp = out + (size_t)arow * D + koff;
  float4 h0[4], h1[4];
#pragma unroll
  for (int ks = 0; ks < 4; ++ks) {
    h0[ks] = *(const float4*)(hp + ks * 32);
    h1[ks] = *(const float4*)(hp + ks * 32 + 4);
  }

  // stage Wt into LDS (padded rows: 264 bf16 = 132 dwords -> balanced banks)
#pragma unroll
  for (int i = 0; i < 8; ++i) {
    int idx = tid + i * 512;  // 0..4095 chunks of 16B
    int row = idx >> 5, seg = idx & 31;
    uint4 v = *(const uint4*)(wt + row * 256 + seg * 8);
    *(uint4*)(&wt_lds[row * 264 + seg * 8]) = v;
  }

  // convert h -> bf16 frags
#pragma unroll
  for (int ks = 0; ks < 4; ++ks) {
    bf16x8 a;
    a[0] = (short)f2bf(h0[ks].x); a[1] = (short)f2bf(h0[ks].y);
    a[2] = (short)f2bf(h0[ks].z); a[3] = (short)f2bf(h0[ks].w);
    a[4] = (short)f2bf(h1[ks].x); a[5] = (short)f2bf(h1[ks].y);
    a[6] = (short)f2bf(h1[ks].z); a[7] = (short)f2bf(h1[ks].w);
    afrag[4 + ks] = a;
  }
  __syncthreads();

  f32x4 acc[8];
  const f32x4 zero = {0.f, 0.f, 0.f, 0.f};
#pragma unroll
  for (int ct = 0; ct < 8; ++ct) acc[ct] = zero;

#pragma unroll
  for (int ks = 0; ks < 8; ++ks) {
#pragma unroll
    for (int ct = 0; ct < 8; ++ct) {
      bf16x8 b = *(const bf16x8*)(&wt_lds[(ct * 16 + li) * 264 + ks * 32 + koff]);
      acc[ct] = __builtin_amdgcn_mfma_f32_16x16x32_bf16(afrag[ks], b, acc[ct], 0, 0, 0);
    }
  }

  // epilogue: D elem (row=(l>>4)*4+j, col=l&15) per 16-col tile
#pragma unroll
  for (int ct = 0; ct < 8; ++ct) {
    int c = ct * 16 + li;
    float bv = bias[c];
#pragma unroll
    for (int j = 0; j < 4; ++j) {
      int row = r0 + lg * 4 + j;
      if (row < N_NODES) out[(size_t)row * D + c] = acc[ct][j] + bv;
    }
  }
}

// ---------------------------------------------------------------------------
// Fallback fp32 path (used only if ws_size is too small for bf16 buffers)
// ---------------------------------------------------------------------------
__global__ __launch_bounds__(256) void aggregate_f32_kernel(
    const float* __restrict__ feat, const int* __restrict__ offs,
    const int* __restrict__ eidx, float* __restrict__ h) {
  int g = (blockIdx.x * blockDim.x + threadIdx.x) >> 5;
  int lane = threadIdx.x & 31;
  if (g >= N_NODES) return;
  int beg = offs[g], end = offs[g + 1];
  float4 acc = {0.f, 0.f, 0.f, 0.f};
  for (int j = beg; j < end; ++j) {
    int s = eidx[j];
    float4 f = *reinterpret_cast<const float4*>(feat + (size_t)s * D + lane * 4);
    acc.x += f.x; acc.y += f.y; acc.z += f.z; acc.w += f.w;
  }
  float scale = 1.0f / fmaxf((float)(end - beg), 1.0f);
  float4 o = {acc.x * scale, acc.y * scale, acc.z * scale, acc.w * scale};
  *reinterpret_cast<float4*>(h + (size_t)g * D + lane * 4) = o;
}

__global__ __launch_bounds__(256) void gemm_f32_kernel(
    const float* __restrict__ feat, const float* __restrict__ Ws,
    const float* __restrict__ Wn, const float* __restrict__ bias,
    float* __restrict__ out) {
  __shared__ float f_lds[64][132];
  __shared__ float h_lds[64][132];
  const int tid = threadIdx.x;
  const int r0 = blockIdx.x * 64;
  {
    int row = tid >> 2;
    int c0 = (tid & 3) * 32;
    int r = r0 + row;
    if (r < N_NODES) {
      const float* fs = feat + (size_t)r * D + c0;
      const float* hs = out + (size_t)r * D + c0;
#pragma unroll
      for (int j = 0; j < 8; ++j) {
        float4 a = *reinterpret_cast<const float4*>(fs + j * 4);
        float4 b = *reinterpret_cast<const float4*>(hs + j * 4);
        *reinterpret_cast<float4*>(&f_lds[row][c0 + j * 4]) = a;
        *reinterpret_cast<float4*>(&h_lds[row][c0 + j * 4]) = b;
      }
    } else {
      float4 z = {0.f, 0.f, 0.f, 0.f};
#pragma unroll
      for (int j = 0; j < 8; ++j) {
        *reinterpret_cast<float4*>(&f_lds[row][c0 + j * 4]) = z;
        *reinterpret_cast<float4*>(&h_lds[row][c0 + j * 4]) = z;
      }
    }
  }
  __syncthreads();
  const int rs = tid & 15;
  const int n = (tid >> 4) * 8;
  float acc[4][8];
#pragma unroll
  for (int m = 0; m < 4; ++m)
#pragma unroll
    for (int j = 0; j < 8; ++j) acc[m][j] = 0.f;
#pragma unroll 4
  for (int k = 0; k < D; ++k) {
    float4 w0 = *reinterpret_cast<const float4*>(Ws + k * D + n);
    float4 w1 = *reinterpret_cast<const float4*>(Ws + k * D + n + 4);
    float4 v0 = *reinterpret_cast<const float4*>(Wn + k * D + n);
    float4 v1 = *reinterpret_cast<const float4*>(Wn + k * D + n + 4);
#pragma unroll
    for (int m = 0; m < 4; ++m) {
      float xf = f_lds[rs + m * 16][k];
      float xh = h_lds[rs + m * 16][k];
      acc[m][0] = fmaf(xf, w0.x, fmaf(xh, v0.x, acc[m][0]));
      acc[m][1] = fmaf(xf, w0.y, fmaf(xh, v0.y, acc[m][1]));
      acc[m][2] = fmaf(xf, w0.z, fmaf(xh, v0.z, acc[m][2]));
      acc[m][3] = fmaf(xf, w0.w, fmaf(xh, v0.w, acc[m][3]));
      acc[m][4] = fmaf(xf, w1.x, fmaf(xh, v1.x, acc[m][4]));
      acc[m][5] = fmaf(xf, w1.y, fmaf(xh, v1.y, acc[m][5]));
      acc[m][6] = fmaf(xf, w1.z, fmaf(xh, v1.z, acc[m][6]));
      acc[m][7] = fmaf(xf, w1.w, fmaf(xh, v1.w, acc[m][7]));
    }
  }
  float4 b0 = *reinterpret_cast<const float4*>(bias + n);
  float4 b1 = *reinterpret_cast<const float4*>(bias + n + 4);
#pragma unroll
  for (int m = 0; m < 4; ++m) {
    int r = r0 + rs + m * 16;
    if (r < N_NODES) {
      float4 o0 = {acc[m][0] + b0.x, acc[m][1] + b0.y, acc[m][2] + b0.z, acc[m][3] + b0.w};
      float4 o1 = {acc[m][4] + b1.x, acc[m][5] + b1.y, acc[m][6] + b1.z, acc[m][7] + b1.w};
      *reinterpret_cast<float4*>(out + (size_t)r * D + n) = o0;
      *reinterpret_cast<float4*>(out + (size_t)r * D + n + 4) = o1;
    }
  }
}

// ---------------------------------------------------------------------------
extern "C" void kernel_launch(void* const* d_in, const int* in_sizes, int n_in,
                              void* d_out, int out_size, void* d_ws, size_t ws_size,
                              hipStream_t stream) {
  const float* feat = (const float*)d_in[0];
  const int* src    = (const int*)d_in[1];
  const int* dst    = (const int*)d_in[2];
  const float* Ws   = (const float*)d_in[3];
  const float* Wn   = (const float*)d_in[4];
  const float* bias = (const float*)d_in[5];
  float* out = (float*)d_out;

  // workspace layout
  int* offs   = (int*)d_ws;                       // 50004
  int* deg    = offs + 50004;                     // 50000
  int* cursor = deg + 50000;                      // 50000
  int* eidx   = cursor + 50000;                   // 800000
  int* bsum   = eidx + N_EDGES;                   // 64
  unsigned short* fb = (unsigned short*)(bsum + 64);        // 6.4M bf16
  unsigned short* wt = fb + (size_t)N_NODES * D;            // 32768 bf16
  size_t need = (size_t)((char*)(wt + 32768) - (char*)d_ws);

  hipMemsetAsync(deg, 0, N_NODES * sizeof(int), stream);
  hipMemsetAsync(cursor, 0, N_NODES * sizeof(int), stream);

  deg_kernel<<<3125, 256, 0, stream>>>(dst, deg);
  scan_local_kernel<<<49, 1024, 0, stream>>>(deg, offs, bsum);
  scan_bsum_kernel<<<1, 64, 0, stream>>>(bsum, offs);
  add_carry_kernel<<<196, 256, 0, stream>>>(offs, bsum);
  fill_kernel<<<3125, 256, 0, stream>>>(src, dst, offs, cursor, eidx);

  if (ws_size >= need) {
    cvt_feat_kernel<<<3125, 256, 0, stream>>>(feat, fb);
    prepack_w_kernel<<<128, 256, 0, stream>>>(Ws, Wn, wt);
    aggregate_bf_kernel<<<3125, 256, 0, stream>>>(fb, offs, eidx, out);
    gemm_mfma_kernel<<<391, 512, 0, stream>>>(fb, wt, bias, out);
  } else {
    aggregate_f32_kernel<<<(N_NODES * 32 + 255) / 256, 256, 0, stream>>>(feat, offs, eidx, out);
    gemm_f32_kernel<<<(N_NODES + 63) / 64, 256, 0, stream>>>(feat, Ws, Wn, bias, out);
  }
}

// Round 5
// 193.093 us; speedup vs baseline: 1.8019x; 1.1855x over previous
//
#include <hip/hip_runtime.h>

#define N_NODES 50000
#define N_EDGES 800000
#define D 128

typedef __attribute__((ext_vector_type(8))) short bf16x8;
typedef __attribute__((ext_vector_type(4))) float f32x4;

__device__ __forceinline__ unsigned short f2bf(float f) {
  unsigned u = __float_as_uint(f);
  u = (u + 0x7FFFu + ((u >> 16) & 1u)) >> 16;  // RNE
  return (unsigned short)u;
}

// ---------------------------------------------------------------------------
// feat fp32 -> bf16 (6.4M elems, 8 per thread, exact 800000-thread grid)
// ---------------------------------------------------------------------------
__global__ void cvt_feat_kernel(const float* __restrict__ feat,
                                unsigned short* __restrict__ fb) {
  int i = blockIdx.x * blockDim.x + threadIdx.x;
  float4 a = ((const float4*)feat)[2 * i];
  float4 b = ((const float4*)feat)[2 * i + 1];
  union { unsigned short s[8]; uint4 u; } p;
  p.s[0] = f2bf(a.x); p.s[1] = f2bf(a.y); p.s[2] = f2bf(a.z); p.s[3] = f2bf(a.w);
  p.s[4] = f2bf(b.x); p.s[5] = f2bf(b.y); p.s[6] = f2bf(b.z); p.s[7] = f2bf(b.w);
  ((uint4*)fb)[i] = p.u;
}

// ---------------------------------------------------------------------------
// W prepack: wt[n*256 + k] = bf16(Wcat[k][n]), Wcat = [Ws; Wn] (256 x 128)
// ---------------------------------------------------------------------------
__global__ void prepack_w_kernel(const float* __restrict__ Ws,
                                 const float* __restrict__ Wn,
                                 unsigned short* __restrict__ wt) {
  int t = blockIdx.x * blockDim.x + threadIdx.x;  // 32768
  int n = t >> 8, k = t & 255;
  float v = (k < 128) ? Ws[k * 128 + n] : Wn[(k - 128) * 128 + n];
  wt[t] = f2bf(v);
}

// ---------------------------------------------------------------------------
// K1: build per-dst linked lists in ONE pass.
// head[d] must be -1-initialized (memset 0xFF). next[e] write is coalesced.
// ---------------------------------------------------------------------------
__global__ void build_chain_kernel(const int* __restrict__ dst,
                                   int* __restrict__ head,
                                   int* __restrict__ next) {
  int e = blockIdx.x * blockDim.x + threadIdx.x;
  if (e < N_EDGES) {
    int d = dst[e];
    int old = atomicExch(&head[d], e);
    next[e] = old;
  }
}

// ---------------------------------------------------------------------------
// K2: chain-walk gather-mean over bf16 feat; 16 lanes/node, 16B/lane.
// next[e]/src[e] loads are same-address within the 16-lane group (broadcast);
// src-load and next-load are independent per step -> overlap.
// Writes h (fp32) into d_out (consumed in-place by the GEMM).
// ---------------------------------------------------------------------------
__global__ __launch_bounds__(256) void aggregate_chain_bf_kernel(
    const unsigned short* __restrict__ fb, const int* __restrict__ head,
    const int* __restrict__ next, const int* __restrict__ src,
    float* __restrict__ h) {
  int g = (blockIdx.x * blockDim.x + threadIdx.x) >> 4;
  int lane = threadIdx.x & 15;
  if (g >= N_NODES) return;
  const unsigned short* fl = fb + lane * 8;
  float acc[8] = {0.f, 0.f, 0.f, 0.f, 0.f, 0.f, 0.f, 0.f};
  int cnt = 0;
  int e = head[g];
  while (e >= 0) {
    int s = src[e];
    int en = next[e];  // independent of the gather; issues alongside
    uint4 v = *(const uint4*)(fl + (size_t)s * D);
    acc[0] += __uint_as_float(v.x << 16);
    acc[1] += __uint_as_float(v.x & 0xFFFF0000u);
    acc[2] += __uint_as_float(v.y << 16);
    acc[3] += __uint_as_float(v.y & 0xFFFF0000u);
    acc[4] += __uint_as_float(v.z << 16);
    acc[5] += __uint_as_float(v.z & 0xFFFF0000u);
    acc[6] += __uint_as_float(v.w << 16);
    acc[7] += __uint_as_float(v.w & 0xFFFF0000u);
    ++cnt;
    e = en;
  }
  float scale = (cnt > 0) ? (1.0f / (float)cnt) : 0.0f;
  float* op = h + (size_t)g * D + lane * 8;
  float4 o0 = {acc[0] * scale, acc[1] * scale, acc[2] * scale, acc[3] * scale};
  float4 o1 = {acc[4] * scale, acc[5] * scale, acc[6] * scale, acc[7] * scale};
  *(float4*)op = o0;
  *(float4*)(op + 4) = o1;
}

// ---------------------------------------------------------------------------
// K3: MFMA GEMM: out = [fb | bf16(h)] @ Wcat + bias, h read in-place from out.
// 512 thr = 8 waves x 16 rows = 128 rows/block. Wt (n-major, pad 264) in LDS.
// All h reads happen before the single barrier; all out writes after ->
// in-place safe (clamped tail reads stay within the last block).
// ---------------------------------------------------------------------------
__global__ __launch_bounds__(512) void gemm_mfma_kernel(
    const unsigned short* __restrict__ fb, const unsigned short* __restrict__ wt,
    const float* __restrict__ bias, float* out) {
  __shared__ unsigned short wt_lds[128 * 264];  // 67584 B
  const int tid = threadIdx.x;
  const int w = tid >> 6;
  const int l = tid & 63;
  const int li = l & 15;
  const int lg = l >> 4;
  const int koff = lg * 8;
  const int r0 = blockIdx.x * 128 + w * 16;
  int arow = r0 + li;
  if (arow > N_NODES - 1) arow = N_NODES - 1;  // clamp; results discarded

  // A prefetch: feat half (bf16 direct)
  bf16x8 afrag[8];
  const unsigned short* fbp = fb + (size_t)arow * D + koff;
#pragma unroll
  for (int ks = 0; ks < 4; ++ks)
    afrag[ks] = *(const bf16x8*)(fbp + ks * 32);
  // A prefetch: h half (fp32 from out, convert below)
  const float* hp = out + (size_t)arow * D + koff;
  float4 h0[4], h1[4];
#pragma unroll
  for (int ks = 0; ks < 4; ++ks) {
    h0[ks] = *(const float4*)(hp + ks * 32);
    h1[ks] = *(const float4*)(hp + ks * 32 + 4);
  }

  // stage Wt into LDS (padded rows: 264 bf16 -> balanced banks)
#pragma unroll
  for (int i = 0; i < 8; ++i) {
    int idx = tid + i * 512;  // 0..4095 chunks of 16B
    int row = idx >> 5, seg = idx & 31;
    uint4 v = *(const uint4*)(wt + row * 256 + seg * 8);
    *(uint4*)(&wt_lds[row * 264 + seg * 8]) = v;
  }

  // convert h -> bf16 frags
#pragma unroll
  for (int ks = 0; ks < 4; ++ks) {
    bf16x8 a;
    a[0] = (short)f2bf(h0[ks].x); a[1] = (short)f2bf(h0[ks].y);
    a[2] = (short)f2bf(h0[ks].z); a[3] = (short)f2bf(h0[ks].w);
    a[4] = (short)f2bf(h1[ks].x); a[5] = (short)f2bf(h1[ks].y);
    a[6] = (short)f2bf(h1[ks].z); a[7] = (short)f2bf(h1[ks].w);
    afrag[4 + ks] = a;
  }
  __syncthreads();

  f32x4 acc[8];
  const f32x4 zero = {0.f, 0.f, 0.f, 0.f};
#pragma unroll
  for (int ct = 0; ct < 8; ++ct) acc[ct] = zero;

#pragma unroll
  for (int ks = 0; ks < 8; ++ks) {
#pragma unroll
    for (int ct = 0; ct < 8; ++ct) {
      bf16x8 b = *(const bf16x8*)(&wt_lds[(ct * 16 + li) * 264 + ks * 32 + koff]);
      acc[ct] = __builtin_amdgcn_mfma_f32_16x16x32_bf16(afrag[ks], b, acc[ct], 0, 0, 0);
    }
  }

  // epilogue: D elem (row=(l>>4)*4+j, col=l&15) per 16-col tile
#pragma unroll
  for (int ct = 0; ct < 8; ++ct) {
    int c = ct * 16 + li;
    float bv = bias[c];
#pragma unroll
    for (int j = 0; j < 4; ++j) {
      int row = r0 + lg * 4 + j;
      if (row < N_NODES) out[(size_t)row * D + c] = acc[ct][j] + bv;
    }
  }
}

// ---------------------------------------------------------------------------
// Fallback fp32 path (only if ws_size < ~15.6 MB): chain aggregate on fp32
// feat + in-place fp32 GEMM. Needs only head+next (3.4 MB).
// ---------------------------------------------------------------------------
__global__ __launch_bounds__(256) void aggregate_chain_f32_kernel(
    const float* __restrict__ feat, const int* __restrict__ head,
    const int* __restrict__ next, const int* __restrict__ src,
    float* __restrict__ h) {
  int g = (blockIdx.x * blockDim.x + threadIdx.x) >> 5;
  int lane = threadIdx.x & 31;
  if (g >= N_NODES) return;
  float4 acc = {0.f, 0.f, 0.f, 0.f};
  int cnt = 0;
  int e = head[g];
  while (e >= 0) {
    int s = src[e];
    int en = next[e];
    float4 f = *reinterpret_cast<const float4*>(feat + (size_t)s * D + lane * 4);
    acc.x += f.x; acc.y += f.y; acc.z += f.z; acc.w += f.w;
    ++cnt;
    e = en;
  }
  float scale = (cnt > 0) ? (1.0f / (float)cnt) : 0.0f;
  float4 o = {acc.x * scale, acc.y * scale, acc.z * scale, acc.w * scale};
  *reinterpret_cast<float4*>(h + (size_t)g * D + lane * 4) = o;
}

__global__ __launch_bounds__(256) void gemm_f32_kernel(
    const float* __restrict__ feat, const float* __restrict__ Ws,
    const float* __restrict__ Wn, const float* __restrict__ bias,
    float* __restrict__ out) {
  __shared__ float f_lds[64][132];
  __shared__ float h_lds[64][132];
  const int tid = threadIdx.x;
  const int r0 = blockIdx.x * 64;
  {
    int row = tid >> 2;
    int c0 = (tid & 3) * 32;
    int r = r0 + row;
    if (r < N_NODES) {
      const float* fs = feat + (size_t)r * D + c0;
      const float* hs = out + (size_t)r * D + c0;
#pragma unroll
      for (int j = 0; j < 8; ++j) {
        float4 a = *reinterpret_cast<const float4*>(fs + j * 4);
        float4 b = *reinterpret_cast<const float4*>(hs + j * 4);
        *reinterpret_cast<float4*>(&f_lds[row][c0 + j * 4]) = a;
        *reinterpret_cast<float4*>(&h_lds[row][c0 + j * 4]) = b;
      }
    } else {
      float4 z = {0.f, 0.f, 0.f, 0.f};
#pragma unroll
      for (int j = 0; j < 8; ++j) {
        *reinterpret_cast<float4*>(&f_lds[row][c0 + j * 4]) = z;
        *reinterpret_cast<float4*>(&h_lds[row][c0 + j * 4]) = z;
      }
    }
  }
  __syncthreads();
  const int rs = tid & 15;
  const int n = (tid >> 4) * 8;
  float acc[4][8];
#pragma unroll
  for (int m = 0; m < 4; ++m)
#pragma unroll
    for (int j = 0; j < 8; ++j) acc[m][j] = 0.f;
#pragma unroll 4
  for (int k = 0; k < D; ++k) {
    float4 w0 = *reinterpret_cast<const float4*>(Ws + k * D + n);
    float4 w1 = *reinterpret_cast<const float4*>(Ws + k * D + n + 4);
    float4 v0 = *reinterpret_cast<const float4*>(Wn + k * D + n);
    float4 v1 = *reinterpret_cast<const float4*>(Wn + k * D + n + 4);
#pragma unroll
    for (int m = 0; m < 4; ++m) {
      float xf = f_lds[rs + m * 16][k];
      float xh = h_lds[rs + m * 16][k];
      acc[m][0] = fmaf(xf, w0.x, fmaf(xh, v0.x, acc[m][0]));
      acc[m][1] = fmaf(xf, w0.y, fmaf(xh, v0.y, acc[m][1]));
      acc[m][2] = fmaf(xf, w0.z, fmaf(xh, v0.z, acc[m][2]));
      acc[m][3] = fmaf(xf, w0.w, fmaf(xh, v0.w, acc[m][3]));
      acc[m][4] = fmaf(xf, w1.x, fmaf(xh, v1.x, acc[m][4]));
      acc[m][5] = fmaf(xf, w1.y, fmaf(xh, v1.y, acc[m][5]));
      acc[m][6] = fmaf(xf, w1.z, fmaf(xh, v1.z, acc[m][6]));
      acc[m][7] = fmaf(xf, w1.w, fmaf(xh, v1.w, acc[m][7]));
    }
  }
  float4 b0 = *reinterpret_cast<const float4*>(bias + n);
  float4 b1 = *reinterpret_cast<const float4*>(bias + n + 4);
#pragma unroll
  for (int m = 0; m < 4; ++m) {
    int r = r0 + rs + m * 16;
    if (r < N_NODES) {
      float4 o0 = {acc[m][0] + b0.x, acc[m][1] + b0.y, acc[m][2] + b0.z, acc[m][3] + b0.w};
      float4 o1 = {acc[m][4] + b1.x, acc[m][5] + b1.y, acc[m][6] + b1.z, acc[m][7] + b1.w};
      *reinterpret_cast<float4*>(out + (size_t)r * D + n) = o0;
      *reinterpret_cast<float4*>(out + (size_t)r * D + n + 4) = o1;
    }
  }
}

// ---------------------------------------------------------------------------
extern "C" void kernel_launch(void* const* d_in, const int* in_sizes, int n_in,
                              void* d_out, int out_size, void* d_ws, size_t ws_size,
                              hipStream_t stream) {
  const float* feat = (const float*)d_in[0];
  const int* src    = (const int*)d_in[1];
  const int* dst    = (const int*)d_in[2];
  const float* Ws   = (const float*)d_in[3];
  const float* Wn   = (const float*)d_in[4];
  const float* bias = (const float*)d_in[5];
  float* out = (float*)d_out;

  // workspace layout (~15.6 MB full path)
  int* head = (int*)d_ws;                          // 50176 (padded)
  int* next = head + 50176;                        // 800000
  unsigned short* fb = (unsigned short*)(next + N_EDGES);   // 6.4M bf16
  unsigned short* wt = fb + (size_t)N_NODES * D;            // 32768 bf16
  size_t need_full = (size_t)((char*)(wt + 32768) - (char*)d_ws);
  size_t need_min  = (size_t)((char*)(next + N_EDGES) - (char*)d_ws);

  hipMemsetAsync(head, 0xFF, 50176 * sizeof(int), stream);  // head[] = -1
  build_chain_kernel<<<3125, 256, 0, stream>>>(dst, head, next);

  if (ws_size >= need_full) {
    cvt_feat_kernel<<<3125, 256, 0, stream>>>(feat, fb);
    prepack_w_kernel<<<128, 256, 0, stream>>>(Ws, Wn, wt);
    aggregate_chain_bf_kernel<<<3125, 256, 0, stream>>>(fb, head, next, src, out);
    gemm_mfma_kernel<<<391, 512, 0, stream>>>(fb, wt, bias, out);
  } else if (ws_size >= need_min) {
    aggregate_chain_f32_kernel<<<6250, 256, 0, stream>>>(feat, head, next, src, out);
    gemm_f32_kernel<<<(N_NODES + 63) / 64, 256, 0, stream>>>(feat, Ws, Wn, bias, out);
  }
}

// Round 7
// 185.636 us; speedup vs baseline: 1.8742x; 1.0402x over previous
//
#include <hip/hip_runtime.h>

#define N_NODES 50000
#define N_EDGES 800000
#define D 128
#define NBUCKET 4
#define BUCKET_W 12500  // N_NODES / NBUCKET

typedef __attribute__((ext_vector_type(8))) short bf16x8;
typedef __attribute__((ext_vector_type(4))) float f32x4;

__device__ __forceinline__ unsigned short f2bf(float f) {
  unsigned u = __float_as_uint(f);
  u = (u + 0x7FFFu + ((u >> 16) & 1u)) >> 16;  // RNE
  return (unsigned short)u;
}

// ---------------------------------------------------------------------------
// K1 (fused): feat fp32->bf16 cvt  +  bucketed chain build.
// Thread i handles feat chunk i (8 floats) and edge i.
// head[bucket][d] = -1 pre-init via memset. next[e] write is coalesced.
// ---------------------------------------------------------------------------
__global__ void prep_kernel(const float* __restrict__ feat,
                            unsigned short* __restrict__ fb,
                            const int* __restrict__ src,
                            const int* __restrict__ dst,
                            int* __restrict__ head,
                            int* __restrict__ next) {
  int i = blockIdx.x * blockDim.x + threadIdx.x;  // exactly 800000 threads
  // --- cvt: 8 floats -> 8 bf16
  float4 a = ((const float4*)feat)[2 * i];
  float4 b = ((const float4*)feat)[2 * i + 1];
  union { unsigned short s[8]; uint4 u; } p;
  p.s[0] = f2bf(a.x); p.s[1] = f2bf(a.y); p.s[2] = f2bf(a.z); p.s[3] = f2bf(a.w);
  p.s[4] = f2bf(b.x); p.s[5] = f2bf(b.y); p.s[6] = f2bf(b.z); p.s[7] = f2bf(b.w);
  ((uint4*)fb)[i] = p.u;
  // --- chain build, bucketed by src range
  int s = src[i];
  int d = dst[i];
  int bucket = s / BUCKET_W;  // 0..3
  int old = atomicExch(&head[bucket * N_NODES + d], i);
  next[i] = old;
}

// ---------------------------------------------------------------------------
// W prepack: wt[n*256 + k] = bf16(Wcat[k][n]), Wcat = [Ws; Wn] (256 x 128)
// ---------------------------------------------------------------------------
__global__ void prepack_w_kernel(const float* __restrict__ Ws,
                                 const float* __restrict__ Wn,
                                 unsigned short* __restrict__ wt) {
  int t = blockIdx.x * blockDim.x + threadIdx.x;  // 32768
  int n = t >> 8, k = t & 255;
  float v = (k < 128) ? Ws[k * 128 + n] : Wn[(k - 128) * 128 + n];
  wt[t] = f2bf(v);
}

// ---------------------------------------------------------------------------
// K2: bucketed chain-walk gather-mean; 16 lanes/node, 16B/lane.
// Buckets processed in order -> the whole GPU gathers from a ~3.2MB feat
// slice at a time, which stays resident in every XCD's 4MB L2.
// Writes h (fp32) into d_out (consumed in-place by the GEMM).
// ---------------------------------------------------------------------------
__global__ __launch_bounds__(256) void aggregate_chain_bf_kernel(
    const unsigned short* __restrict__ fb, const int* __restrict__ head,
    const int* __restrict__ next, const int* __restrict__ src,
    float* __restrict__ h) {
  int g = (blockIdx.x * blockDim.x + threadIdx.x) >> 4;
  int lane = threadIdx.x & 15;
  if (g >= N_NODES) return;
  const unsigned short* fl = fb + lane * 8;
  float acc[8] = {0.f, 0.f, 0.f, 0.f, 0.f, 0.f, 0.f, 0.f};
  int cnt = 0;
#pragma unroll
  for (int b = 0; b < NBUCKET; ++b) {
    int e = head[b * N_NODES + g];
    while (e >= 0) {
      int s = src[e];
      int en = next[e];  // independent of the gather; issues alongside
      uint4 v = *(const uint4*)(fl + (size_t)s * D);
      acc[0] += __uint_as_float(v.x << 16);
      acc[1] += __uint_as_float(v.x & 0xFFFF0000u);
      acc[2] += __uint_as_float(v.y << 16);
      acc[3] += __uint_as_float(v.y & 0xFFFF0000u);
      acc[4] += __uint_as_float(v.z << 16);
      acc[5] += __uint_as_float(v.z & 0xFFFF0000u);
      acc[6] += __uint_as_float(v.w << 16);
      acc[7] += __uint_as_float(v.w & 0xFFFF0000u);
      ++cnt;
      e = en;
    }
  }
  float scale = (cnt > 0) ? (1.0f / (float)cnt) : 0.0f;
  float* op = h + (size_t)g * D + lane * 8;
  float4 o0 = {acc[0] * scale, acc[1] * scale, acc[2] * scale, acc[3] * scale};
  float4 o1 = {acc[4] * scale, acc[5] * scale, acc[6] * scale, acc[7] * scale};
  *(float4*)op = o0;
  *(float4*)(op + 4) = o1;
}

// ---------------------------------------------------------------------------
// K3: MFMA GEMM: out = [fb | bf16(h)] @ Wcat + bias, h read in-place from out.
// 512 thr = 8 waves x 16 rows = 128 rows/block. Wt (n-major, pad 264) in LDS.
// All h reads happen before the single barrier; all out writes after ->
// in-place safe (clamped tail reads stay within the last block).
// ---------------------------------------------------------------------------
__global__ __launch_bounds__(512) void gemm_mfma_kernel(
    const unsigned short* __restrict__ fb, const unsigned short* __restrict__ wt,
    const float* __restrict__ bias, float* out) {
  __shared__ unsigned short wt_lds[128 * 264];  // 67584 B
  const int tid = threadIdx.x;
  const int w = tid >> 6;
  const int l = tid & 63;
  const int li = l & 15;
  const int lg = l >> 4;
  const int koff = lg * 8;
  const int r0 = blockIdx.x * 128 + w * 16;
  int arow = r0 + li;
  if (arow > N_NODES - 1) arow = N_NODES - 1;  // clamp; results discarded

  // A prefetch: feat half (bf16 direct)
  bf16x8 afrag[8];
  const unsigned short* fbp = fb + (size_t)arow * D + koff;
#pragma unroll
  for (int ks = 0; ks < 4; ++ks)
    afrag[ks] = *(const bf16x8*)(fbp + ks * 32);
  // A prefetch: h half (fp32 from out, convert below)
  const float* hp = out + (size_t)arow * D + koff;
  float4 h0[4], h1[4];
#pragma unroll
  for (int ks = 0; ks < 4; ++ks) {
    h0[ks] = *(const float4*)(hp + ks * 32);
    h1[ks] = *(const float4*)(hp + ks * 32 + 4);
  }

  // stage Wt into LDS (padded rows: 264 bf16 -> balanced banks)
#pragma unroll
  for (int i = 0; i < 8; ++i) {
    int idx = tid + i * 512;  // 0..4095 chunks of 16B
    int row = idx >> 5, seg = idx & 31;
    uint4 v = *(const uint4*)(wt + row * 256 + seg * 8);
    *(uint4*)(&wt_lds[row * 264 + seg * 8]) = v;
  }

  // convert h -> bf16 frags
#pragma unroll
  for (int ks = 0; ks < 4; ++ks) {
    bf16x8 a;
    a[0] = (short)f2bf(h0[ks].x); a[1] = (short)f2bf(h0[ks].y);
    a[2] = (short)f2bf(h0[ks].z); a[3] = (short)f2bf(h0[ks].w);
    a[4] = (short)f2bf(h1[ks].x); a[5] = (short)f2bf(h1[ks].y);
    a[6] = (short)f2bf(h1[ks].z); a[7] = (short)f2bf(h1[ks].w);
    afrag[4 + ks] = a;
  }
  __syncthreads();

  f32x4 acc[8];
  const f32x4 zero = {0.f, 0.f, 0.f, 0.f};
#pragma unroll
  for (int ct = 0; ct < 8; ++ct) acc[ct] = zero;

#pragma unroll
  for (int ks = 0; ks < 8; ++ks) {
#pragma unroll
    for (int ct = 0; ct < 8; ++ct) {
      bf16x8 b = *(const bf16x8*)(&wt_lds[(ct * 16 + li) * 264 + ks * 32 + koff]);
      acc[ct] = __builtin_amdgcn_mfma_f32_16x16x32_bf16(afrag[ks], b, acc[ct], 0, 0, 0);
    }
  }

  // epilogue: D elem (row=(l>>4)*4+j, col=l&15) per 16-col tile
#pragma unroll
  for (int ct = 0; ct < 8; ++ct) {
    int c = ct * 16 + li;
    float bv = bias[c];
#pragma unroll
    for (int j = 0; j < 4; ++j) {
      int row = r0 + lg * 4 + j;
      if (row < N_NODES) out[(size_t)row * D + c] = acc[ct][j] + bv;
    }
  }
}

// ---------------------------------------------------------------------------
// Fallback fp32 path (only if ws_size < ~16.9 MB): bucketed chain aggregate
// on fp32 feat + in-place fp32 GEMM. Needs only head+next (4.0 MB).
// ---------------------------------------------------------------------------
__global__ void build_chain_f32_kernel(const int* __restrict__ src,
                                       const int* __restrict__ dst,
                                       int* __restrict__ head,
                                       int* __restrict__ next) {
  int e = blockIdx.x * blockDim.x + threadIdx.x;
  if (e < N_EDGES) {
    int s = src[e];
    int d = dst[e];
    int bucket = s / BUCKET_W;
    int old = atomicExch(&head[bucket * N_NODES + d], e);
    next[e] = old;
  }
}

__global__ __launch_bounds__(256) void aggregate_chain_f32_kernel(
    const float* __restrict__ feat, const int* __restrict__ head,
    const int* __restrict__ next, const int* __restrict__ src,
    float* __restrict__ h) {
  int g = (blockIdx.x * blockDim.x + threadIdx.x) >> 5;
  int lane = threadIdx.x & 31;
  if (g >= N_NODES) return;
  float4 acc = {0.f, 0.f, 0.f, 0.f};
  int cnt = 0;
#pragma unroll
  for (int b = 0; b < NBUCKET; ++b) {
    int e = head[b * N_NODES + g];
    while (e >= 0) {
      int s = src[e];
      int en = next[e];
      float4 f = *reinterpret_cast<const float4*>(feat + (size_t)s * D + lane * 4);
      acc.x += f.x; acc.y += f.y; acc.z += f.z; acc.w += f.w;
      ++cnt;
      e = en;
    }
  }
  float scale = (cnt > 0) ? (1.0f / (float)cnt) : 0.0f;
  float4 o = {acc.x * scale, acc.y * scale, acc.z * scale, acc.w * scale};
  *reinterpret_cast<float4*>(h + (size_t)g * D + lane * 4) = o;
}

__global__ __launch_bounds__(256) void gemm_f32_kernel(
    const float* __restrict__ feat, const float* __restrict__ Ws,
    const float* __restrict__ Wn, const float* __restrict__ bias,
    float* __restrict__ out) {
  __shared__ float f_lds[64][132];
  __shared__ float h_lds[64][132];
  const int tid = threadIdx.x;
  const int r0 = blockIdx.x * 64;
  {
    int row = tid >> 2;
    int c0 = (tid & 3) * 32;
    int r = r0 + row;
    if (r < N_NODES) {
      const float* fs = feat + (size_t)r * D + c0;
      const float* hs = out + (size_t)r * D + c0;
#pragma unroll
      for (int j = 0; j < 8; ++j) {
        float4 a = *reinterpret_cast<const float4*>(fs + j * 4);
        float4 b = *reinterpret_cast<const float4*>(hs + j * 4);
        *reinterpret_cast<float4*>(&f_lds[row][c0 + j * 4]) = a;
        *reinterpret_cast<float4*>(&h_lds[row][c0 + j * 4]) = b;
      }
    } else {
      float4 z = {0.f, 0.f, 0.f, 0.f};
#pragma unroll
      for (int j = 0; j < 8; ++j) {
        *reinterpret_cast<float4*>(&f_lds[row][c0 + j * 4]) = z;
        *reinterpret_cast<float4*>(&h_lds[row][c0 + j * 4]) = z;
      }
    }
  }
  __syncthreads();
  const int rs = tid & 15;
  const int n = (tid >> 4) * 8;
  float acc[4][8];
#pragma unroll
  for (int m = 0; m < 4; ++m)
#pragma unroll
    for (int j = 0; j < 8; ++j) acc[m][j] = 0.f;
#pragma unroll 4
  for (int k = 0; k < D; ++k) {
    float4 w0 = *reinterpret_cast<const float4*>(Ws + k * D + n);
    float4 w1 = *reinterpret_cast<const float4*>(Ws + k * D + n + 4);
    float4 v0 = *reinterpret_cast<const float4*>(Wn + k * D + n);
    float4 v1 = *reinterpret_cast<const float4*>(Wn + k * D + n + 4);
#pragma unroll
    for (int m = 0; m < 4; ++m) {
      float xf = f_lds[rs + m * 16][k];
      float xh = h_lds[rs + m * 16][k];
      acc[m][0] = fmaf(xf, w0.x, fmaf(xh, v0.x, acc[m][0]));
      acc[m][1] = fmaf(xf, w0.y, fmaf(xh, v0.y, acc[m][1]));
      acc[m][2] = fmaf(xf, w0.z, fmaf(xh, v0.z, acc[m][2]));
      acc[m][3] = fmaf(xf, w0.w, fmaf(xh, v0.w, acc[m][3]));
      acc[m][4] = fmaf(xf, w1.x, fmaf(xh, v1.x, acc[m][4]));
      acc[m][5] = fmaf(xf, w1.y, fmaf(xh, v1.y, acc[m][5]));
      acc[m][6] = fmaf(xf, w1.z, fmaf(xh, v1.z, acc[m][6]));
      acc[m][7] = fmaf(xf, w1.w, fmaf(xh, v1.w, acc[m][7]));
    }
  }
  float4 b0 = *reinterpret_cast<const float4*>(bias + n);
  float4 b1 = *reinterpret_cast<const float4*>(bias + n + 4);
#pragma unroll
  for (int m = 0; m < 4; ++m) {
    int r = r0 + rs + m * 16;
    if (r < N_NODES) {
      float4 o0 = {acc[m][0] + b0.x, acc[m][1] + b0.y, acc[m][2] + b0.z, acc[m][3] + b0.w};
      float4 o1 = {acc[m][4] + b1.x, acc[m][5] + b1.y, acc[m][6] + b1.z, acc[m][7] + b1.w};
      *reinterpret_cast<float4*>(out + (size_t)r * D + n) = o0;
      *reinterpret_cast<float4*>(out + (size_t)r * D + n + 4) = o1;
    }
  }
}

// ---------------------------------------------------------------------------
extern "C" void kernel_launch(void* const* d_in, const int* in_sizes, int n_in,
                              void* d_out, int out_size, void* d_ws, size_t ws_size,
                              hipStream_t stream) {
  const float* feat = (const float*)d_in[0];
  const int* src    = (const int*)d_in[1];
  const int* dst    = (const int*)d_in[2];
  const float* Ws   = (const float*)d_in[3];
  const float* Wn   = (const float*)d_in[4];
  const float* bias = (const float*)d_in[5];
  float* out = (float*)d_out;

  // workspace layout (~16.9 MB full path)
  int* head = (int*)d_ws;                          // NBUCKET * N_NODES
  int* next = head + NBUCKET * N_NODES;            // N_EDGES
  unsigned short* fb = (unsigned short*)(next + N_EDGES);   // 6.4M bf16
  unsigned short* wt = fb + (size_t)N_NODES * D;            // 32768 bf16
  size_t need_full = (size_t)((char*)(wt + 32768) - (char*)d_ws);
  size_t need_min  = (size_t)((char*)(next + N_EDGES) - (char*)d_ws);

  hipMemsetAsync(head, 0xFF, NBUCKET * N_NODES * sizeof(int), stream);

  if (ws_size >= need_full) {
    prep_kernel<<<3125, 256, 0, stream>>>(feat, fb, src, dst, head, next);
    prepack_w_kernel<<<128, 256, 0, stream>>>(Ws, Wn, wt);
    aggregate_chain_bf_kernel<<<3125, 256, 0, stream>>>(fb, head, next, src, out);
    gemm_mfma_kernel<<<391, 512, 0, stream>>>(fb, wt, bias, out);
  } else if (ws_size >= need_min) {
    build_chain_f32_kernel<<<3125, 256, 0, stream>>>(src, dst, head, next);
    aggregate_chain_f32_kernel<<<6250, 256, 0, stream>>>(feat, head, next, src, out);
    gemm_f32_kernel<<<(N_NODES + 63) / 64, 256, 0, stream>>>(feat, Ws, Wn, bias, out);
  }
}